// Round 1
// baseline (1085.535 us; speedup 1.0000x reference)
//
#include <hip/hip_runtime.h>
#include <math.h>

#define NN 48
#define NP 49
#define N2 2304
#define N3 110592
#define NB 8
#define NT 20

typedef float2 cplx;

// acc += d * w  (complex MAC, 4 FMA)
#define CMAC(AR, AI, D, Wv)                                        \
    AR = fmaf((D).x, (Wv).x, AR); AR = fmaf(-(D).y, (Wv).y, AR);   \
    AI = fmaf((D).x, (Wv).y, AI); AI = fmaf((D).y, (Wv).x, AI);

__device__ __forceinline__ void twinit(cplx* W, int t) {
    if (t < NN) {
        float ang = -6.28318530717958647692f * (float)t / (float)NN;
        float s, c;
        sincosf(ang, &s, &c);
        W[t] = make_float2(c, s);
    }
}

// DFT along the SECOND index: O[row][k] = sum_n S[row][n] * W[(n*k)%48]
// thread t: rows 3g..3g+2 (g=t>>4), ks = kt, kt+16, kt+32 (kt=t&15)
__device__ __forceinline__ void dft_rows(cplx (*S)[NP], const cplx* W, int t, int shift) {
    const int g  = t >> 4;
    const int kt = t & 15;
    const int k0 = kt, k1 = kt + 16, k2 = kt + 32;
    float ar[3][3], ai[3][3];   // [row r][k i]
#pragma unroll
    for (int r = 0; r < 3; ++r)
#pragma unroll
        for (int i = 0; i < 3; ++i) { ar[r][i] = 0.f; ai[r][i] = 0.f; }
    int j0 = 0, j1 = 0, j2 = 0;
    for (int n = 0; n < NN; ++n) {
        cplx d0 = S[3*g+0][n];
        cplx d1 = S[3*g+1][n];
        cplx d2 = S[3*g+2][n];
        cplx w0 = W[j0], w1 = W[j1], w2 = W[j2];
        CMAC(ar[0][0], ai[0][0], d0, w0); CMAC(ar[1][0], ai[1][0], d1, w0); CMAC(ar[2][0], ai[2][0], d2, w0);
        CMAC(ar[0][1], ai[0][1], d0, w1); CMAC(ar[1][1], ai[1][1], d1, w1); CMAC(ar[2][1], ai[2][1], d2, w1);
        CMAC(ar[0][2], ai[0][2], d0, w2); CMAC(ar[1][2], ai[1][2], d1, w2); CMAC(ar[2][2], ai[2][2], d2, w2);
        j0 += k0; if (j0 >= NN) j0 -= NN;
        j1 += k1; if (j1 >= NN) j1 -= NN;
        j2 += k2; if (j2 >= NN) j2 -= NN;
    }
    __syncthreads();
#pragma unroll
    for (int i = 0; i < 3; ++i) {
        int k = kt + 16*i;
        if (shift) { k += 24; if (k >= NN) k -= NN; }
        S[3*g+0][k] = make_float2(ar[0][i], ai[0][i]);
        S[3*g+1][k] = make_float2(ar[1][i], ai[1][i]);
        S[3*g+2][k] = make_float2(ar[2][i], ai[2][i]);
    }
    __syncthreads();
}

// DFT along the FIRST index: O[k][z] = sum_n S[n][z] * W[(n*k)%48]
// thread t: ks = 3kg..3kg+2 (kg=t>>4), zs = 3zt..3zt+2 (zt=t&15)
__device__ __forceinline__ void dft_cols(cplx (*S)[NP], const cplx* W, int t, int shift) {
    const int kg = t >> 4;
    const int zt = t & 15;
    const int k0 = 3*kg, k1 = 3*kg + 1, k2 = 3*kg + 2;
    float ar[3][3], ai[3][3];   // [k i][z zi]
#pragma unroll
    for (int i = 0; i < 3; ++i)
#pragma unroll
        for (int z = 0; z < 3; ++z) { ar[i][z] = 0.f; ai[i][z] = 0.f; }
    int j0 = 0, j1 = 0, j2 = 0;
    for (int n = 0; n < NN; ++n) {
        cplx d0 = S[n][3*zt+0];
        cplx d1 = S[n][3*zt+1];
        cplx d2 = S[n][3*zt+2];
        cplx w0 = W[j0], w1 = W[j1], w2 = W[j2];
        CMAC(ar[0][0], ai[0][0], d0, w0); CMAC(ar[0][1], ai[0][1], d1, w0); CMAC(ar[0][2], ai[0][2], d2, w0);
        CMAC(ar[1][0], ai[1][0], d0, w1); CMAC(ar[1][1], ai[1][1], d1, w1); CMAC(ar[1][2], ai[1][2], d2, w1);
        CMAC(ar[2][0], ai[2][0], d0, w2); CMAC(ar[2][1], ai[2][1], d1, w2); CMAC(ar[2][2], ai[2][2], d2, w2);
        j0 += k0; if (j0 >= NN) j0 -= NN;
        j1 += k1; if (j1 >= NN) j1 -= NN;
        j2 += k2; if (j2 >= NN) j2 -= NN;
    }
    __syncthreads();
#pragma unroll
    for (int i = 0; i < 3; ++i) {
        int k = 3*kg + i;
        if (shift) { k += 24; if (k >= NN) k -= NN; }
        S[k][3*zt+0] = make_float2(ar[i][0], ai[i][0]);
        S[k][3*zt+1] = make_float2(ar[i][1], ai[i][1]);
        S[k][3*zt+2] = make_float2(ar[i][2], ai[i][2]);
    }
    __syncthreads();
}

// f (real) -> DFT z, DFT y (both shifted) -> out (complex, partial transform)
__global__ __launch_bounds__(256)
void kA_f(const float* __restrict__ f, cplx* __restrict__ out) {
    __shared__ cplx S[NN][NP];
    __shared__ cplx W[NN];
    const int x = blockIdx.x, b = blockIdx.y, t = threadIdx.x;
    const float* src = f + (size_t)b * N3 + (size_t)x * N2;
    for (int i = t; i < N2; i += 256) S[i / NN][i % NN] = make_float2(src[i], 0.f);
    twinit(W, t);
    __syncthreads();
    dft_rows(S, W, t, 1);   // along z
    dft_cols(S, W, t, 1);   // along y
    cplx* dst = out + (size_t)b * N3 + (size_t)x * N2;
    for (int i = t; i < N2; i += 256) dst[i] = S[i / NN][i % NN];
}

// finalize f_spec: DFT x (shifted), * 1/N3, in place
__global__ __launch_bounds__(256)
void kB_f(cplx* __restrict__ vol) {
    __shared__ cplx S[NN][NP];
    __shared__ cplx W[NN];
    const int y = blockIdx.x, b = blockIdx.y, t = threadIdx.x;
    cplx* base = vol + (size_t)b * N3 + (size_t)y * NN;
    for (int i = t; i < N2; i += 256) { int xr = i / NN, z = i % NN; S[xr][z] = base[(size_t)xr * N2 + z]; }
    twinit(W, t);
    __syncthreads();
    dft_cols(S, W, t, 1);   // along x
    const float inv = 1.f / (float)N3;
    for (int i = t; i < N2; i += 256) {
        int xr = i / NN, z = i % NN;
        cplx v = S[xr][z];
        base[(size_t)xr * N2 + z] = make_float2(v.x * inv, v.y * inv);
    }
}

// a = f_spec * mul (mul==nullptr -> 1); DFT z, DFT y (no shift) -> out
__global__ __launch_bounds__(256)
void kA_mul(const cplx* __restrict__ spec,
            const float* __restrict__ mul0, const float* __restrict__ mul1,
            cplx* __restrict__ out0, cplx* __restrict__ out1) {
    __shared__ cplx S[NN][NP];
    __shared__ cplx W[NN];
    const int x = blockIdx.x, b = blockIdx.y, term = blockIdx.z, t = threadIdx.x;
    const float* mul = term ? mul1 : mul0;
    const cplx* src = spec + (size_t)b * N3 + (size_t)x * N2;
    cplx* out = (term ? out1 : out0) + (size_t)b * N3 + (size_t)x * N2;
    for (int i = t; i < N2; i += 256) {
        cplx v = src[i];
        if (mul) { float m = mul[(size_t)x * N2 + i]; v.x *= m; v.y *= m; }
        S[i / NN][i % NN] = v;
    }
    twinit(W, t);
    __syncthreads();
    dft_rows(S, W, t, 0);
    dft_cols(S, W, t, 0);
    for (int i = t; i < N2; i += 256) out[i] = S[i / NN][i % NN];
}

// DFT x of both a and b slabs (kept in registers), then
// FIN=0: qacc += Re(a*b);  FIN=1: dout = scale * (qacc - Re(a*b))
template <int FIN>
__global__ __launch_bounds__(256)
void kB_prod(const cplx* __restrict__ va, const cplx* __restrict__ vb,
             float* __restrict__ qacc, const float* __restrict__ kn,
             const int* __restrict__ Mv, float* __restrict__ dout) {
    __shared__ cplx SA[NN][NP];
    __shared__ cplx SB[NN][NP];
    __shared__ cplx W[NN];
    const int y = blockIdx.x, b = blockIdx.y, t = threadIdx.x;
    const cplx* pa = va + (size_t)b * N3 + (size_t)y * NN;
    const cplx* pb = vb + (size_t)b * N3 + (size_t)y * NN;
    for (int i = t; i < N2; i += 256) {
        int xr = i / NN, z = i % NN;
        SA[xr][z] = pa[(size_t)xr * N2 + z];
        SB[xr][z] = pb[(size_t)xr * N2 + z];
    }
    twinit(W, t);
    __syncthreads();
    const int kg = t >> 4, zt = t & 15;
    const int k0 = 3*kg, k1 = 3*kg + 1, k2 = 3*kg + 2;
    float Aar[3][3], Aai[3][3], Bar[3][3], Bai[3][3];  // [k i][z zi]
#pragma unroll
    for (int i = 0; i < 3; ++i)
#pragma unroll
        for (int z = 0; z < 3; ++z) { Aar[i][z]=0.f; Aai[i][z]=0.f; Bar[i][z]=0.f; Bai[i][z]=0.f; }
    int j0 = 0, j1 = 0, j2 = 0;
    for (int n = 0; n < NN; ++n) {
        cplx a0 = SA[n][3*zt+0], a1 = SA[n][3*zt+1], a2 = SA[n][3*zt+2];
        cplx b0 = SB[n][3*zt+0], b1 = SB[n][3*zt+1], b2 = SB[n][3*zt+2];
        cplx w0 = W[j0], w1 = W[j1], w2 = W[j2];
        CMAC(Aar[0][0], Aai[0][0], a0, w0); CMAC(Aar[0][1], Aai[0][1], a1, w0); CMAC(Aar[0][2], Aai[0][2], a2, w0);
        CMAC(Aar[1][0], Aai[1][0], a0, w1); CMAC(Aar[1][1], Aai[1][1], a1, w1); CMAC(Aar[1][2], Aai[1][2], a2, w1);
        CMAC(Aar[2][0], Aai[2][0], a0, w2); CMAC(Aar[2][1], Aai[2][1], a1, w2); CMAC(Aar[2][2], Aai[2][2], a2, w2);
        CMAC(Bar[0][0], Bai[0][0], b0, w0); CMAC(Bar[0][1], Bai[0][1], b1, w0); CMAC(Bar[0][2], Bai[0][2], b2, w0);
        CMAC(Bar[1][0], Bai[1][0], b0, w1); CMAC(Bar[1][1], Bai[1][1], b1, w1); CMAC(Bar[1][2], Bai[1][2], b2, w1);
        CMAC(Bar[2][0], Bai[2][0], b0, w2); CMAC(Bar[2][1], Bai[2][1], b1, w2); CMAC(Bar[2][2], Bai[2][2], b2, w2);
        j0 += k0; if (j0 >= NN) j0 -= NN;
        j1 += k1; if (j1 >= NN) j1 -= NN;
        j2 += k2; if (j2 >= NN) j2 -= NN;
    }
    float scale = 1.f;
    if (FIN) {
        float m = (float)(Mv[0] * Mv[0]);
        scale = 4.f * 3.14159265358979323846f * 3.14159265358979323846f / (kn[0] * m);
    }
#pragma unroll
    for (int i = 0; i < 3; ++i) {
        int k = 3*kg + i;
#pragma unroll
        for (int zi = 0; zi < 3; ++zi) {
            int z = 3*zt + zi;
            float pr = Aar[i][zi] * Bar[i][zi] - Aai[i][zi] * Bai[i][zi];
            size_t idx = (size_t)b * N3 + (size_t)k * N2 + (size_t)y * NN + z;
            if (FIN) dout[idx] = scale * (qacc[idx] - pr);
            else     qacc[idx] += pr;
        }
    }
}

extern "C" void kernel_launch(void* const* d_in, const int* in_sizes, int n_in,
                              void* d_out, int out_size, void* d_ws, size_t ws_size,
                              hipStream_t stream) {
    const float* f      = (const float*)d_in[0];
    const float* kn     = (const float*)d_in[1];
    const float* phi    = (const float*)d_in[2];
    const float* psi    = (const float*)d_in[3];
    const float* phipsi = (const float*)d_in[4];
    const int*   Mv     = (const int*)d_in[5];
    float* out = (float*)d_out;

    char* w = (char*)d_ws;
    const size_t volc = (size_t)NB * N3 * sizeof(cplx);   // 7,077,888 B
    cplx*  fspec = (cplx*)(w);
    cplx*  va    = (cplx*)(w + volc);
    cplx*  vb    = (cplx*)(w + 2 * volc);
    float* qacc  = (float*)(w + 3 * volc);                // + 3,538,944 B => 24.8 MB total

    hipMemsetAsync(qacc, 0, (size_t)NB * N3 * sizeof(float), stream);

    kA_f<<<dim3(NN, NB), 256, 0, stream>>>(f, fspec);
    kB_f<<<dim3(NN, NB), 256, 0, stream>>>(fspec);

    for (int tt = 0; tt < NT; ++tt) {
        kA_mul<<<dim3(NN, NB, 2), 256, 0, stream>>>(fspec,
                                                    phi + (size_t)tt * N3,
                                                    psi + (size_t)tt * N3,
                                                    va, vb);
        kB_prod<0><<<dim3(NN, NB), 256, 0, stream>>>(va, vb, qacc, kn, Mv, out);
    }

    kA_mul<<<dim3(NN, NB, 2), 256, 0, stream>>>(fspec, phipsi, nullptr, va, vb);
    kB_prod<1><<<dim3(NN, NB), 256, 0, stream>>>(va, vb, qacc, kn, Mv, out);
}

// Round 2
// 781.926 us; speedup vs baseline: 1.3883x; 1.3883x over previous
//
#include <hip/hip_runtime.h>
#include <math.h>

#define NN 48
#define NP 49
#define N2 2304
#define N3 110592
#define NB 8
#define NT 20
#define TG 5     // t-values per kB_acc block

typedef float2 cplx;

// acc += d * w  (complex MAC, 4 FMA)
#define CMAC(AR, AI, D, Wv)                                        \
    AR = fmaf((D).x, (Wv).x, AR); AR = fmaf(-(D).y, (Wv).y, AR);   \
    AI = fmaf((D).x, (Wv).y, AI); AI = fmaf((D).y, (Wv).x, AI);

__device__ __forceinline__ void twinit(cplx* W, int t) {
    if (t < NN) {
        float ang = -6.28318530717958647692f * (float)t / (float)NN;
        float s, c;
        sincosf(ang, &s, &c);
        W[t] = make_float2(c, s);
    }
}

// DFT along the SECOND index: O[row][k] = sum_n S[row][n] * W[(n*k)%48]
__device__ __forceinline__ void dft_rows(cplx (*S)[NP], const cplx* W, int t, int shift) {
    const int g  = t >> 4;
    const int kt = t & 15;
    const int k0 = kt, k1 = kt + 16, k2 = kt + 32;
    float ar[3][3], ai[3][3];   // [row r][k i]
#pragma unroll
    for (int r = 0; r < 3; ++r)
#pragma unroll
        for (int i = 0; i < 3; ++i) { ar[r][i] = 0.f; ai[r][i] = 0.f; }
    int j0 = 0, j1 = 0, j2 = 0;
    for (int n = 0; n < NN; ++n) {
        cplx d0 = S[3*g+0][n];
        cplx d1 = S[3*g+1][n];
        cplx d2 = S[3*g+2][n];
        cplx w0 = W[j0], w1 = W[j1], w2 = W[j2];
        CMAC(ar[0][0], ai[0][0], d0, w0); CMAC(ar[1][0], ai[1][0], d1, w0); CMAC(ar[2][0], ai[2][0], d2, w0);
        CMAC(ar[0][1], ai[0][1], d0, w1); CMAC(ar[1][1], ai[1][1], d1, w1); CMAC(ar[2][1], ai[2][1], d2, w1);
        CMAC(ar[0][2], ai[0][2], d0, w2); CMAC(ar[1][2], ai[1][2], d1, w2); CMAC(ar[2][2], ai[2][2], d2, w2);
        j0 += k0; if (j0 >= NN) j0 -= NN;
        j1 += k1; if (j1 >= NN) j1 -= NN;
        j2 += k2; if (j2 >= NN) j2 -= NN;
    }
    __syncthreads();
#pragma unroll
    for (int i = 0; i < 3; ++i) {
        int k = kt + 16*i;
        if (shift) { k += 24; if (k >= NN) k -= NN; }
        S[3*g+0][k] = make_float2(ar[0][i], ai[0][i]);
        S[3*g+1][k] = make_float2(ar[1][i], ai[1][i]);
        S[3*g+2][k] = make_float2(ar[2][i], ai[2][i]);
    }
    __syncthreads();
}

// DFT along the FIRST index: O[k][z] = sum_n S[n][z] * W[(n*k)%48]
__device__ __forceinline__ void dft_cols(cplx (*S)[NP], const cplx* W, int t, int shift) {
    const int kg = t >> 4;
    const int zt = t & 15;
    const int k0 = 3*kg, k1 = 3*kg + 1, k2 = 3*kg + 2;
    float ar[3][3], ai[3][3];   // [k i][z zi]
#pragma unroll
    for (int i = 0; i < 3; ++i)
#pragma unroll
        for (int z = 0; z < 3; ++z) { ar[i][z] = 0.f; ai[i][z] = 0.f; }
    int j0 = 0, j1 = 0, j2 = 0;
    for (int n = 0; n < NN; ++n) {
        cplx d0 = S[n][3*zt+0];
        cplx d1 = S[n][3*zt+1];
        cplx d2 = S[n][3*zt+2];
        cplx w0 = W[j0], w1 = W[j1], w2 = W[j2];
        CMAC(ar[0][0], ai[0][0], d0, w0); CMAC(ar[0][1], ai[0][1], d1, w0); CMAC(ar[0][2], ai[0][2], d2, w0);
        CMAC(ar[1][0], ai[1][0], d0, w1); CMAC(ar[1][1], ai[1][1], d1, w1); CMAC(ar[1][2], ai[1][2], d2, w1);
        CMAC(ar[2][0], ai[2][0], d0, w2); CMAC(ar[2][1], ai[2][1], d1, w2); CMAC(ar[2][2], ai[2][2], d2, w2);
        j0 += k0; if (j0 >= NN) j0 -= NN;
        j1 += k1; if (j1 >= NN) j1 -= NN;
        j2 += k2; if (j2 >= NN) j2 -= NN;
    }
    __syncthreads();
#pragma unroll
    for (int i = 0; i < 3; ++i) {
        int k = 3*kg + i;
        if (shift) { k += 24; if (k >= NN) k -= NN; }
        S[k][3*zt+0] = make_float2(ar[i][0], ai[i][0]);
        S[k][3*zt+1] = make_float2(ar[i][1], ai[i][1]);
        S[k][3*zt+2] = make_float2(ar[i][2], ai[i][2]);
    }
    __syncthreads();
}

// f (real) -> DFT z, DFT y (both shifted) -> out
__global__ __launch_bounds__(256)
void kA_f(const float* __restrict__ f, cplx* __restrict__ out) {
    __shared__ cplx S[NN][NP];
    __shared__ cplx W[NN];
    const int x = blockIdx.x, b = blockIdx.y, t = threadIdx.x;
    const float* src = f + (size_t)b * N3 + (size_t)x * N2;
    for (int i = t; i < N2; i += 256) S[i / NN][i % NN] = make_float2(src[i], 0.f);
    twinit(W, t);
    __syncthreads();
    dft_rows(S, W, t, 1);   // along z
    dft_cols(S, W, t, 1);   // along y
    cplx* dst = out + (size_t)b * N3 + (size_t)x * N2;
    for (int i = t; i < N2; i += 256) dst[i] = S[i / NN][i % NN];
}

// finalize f_spec: DFT x (shifted), * 1/N3, in place
__global__ __launch_bounds__(256)
void kB_f(cplx* __restrict__ vol) {
    __shared__ cplx S[NN][NP];
    __shared__ cplx W[NN];
    const int y = blockIdx.x, b = blockIdx.y, t = threadIdx.x;
    cplx* base = vol + (size_t)b * N3 + (size_t)y * NN;
    for (int i = t; i < N2; i += 256) { int xr = i / NN, z = i % NN; S[xr][z] = base[(size_t)xr * N2 + z]; }
    twinit(W, t);
    __syncthreads();
    dft_cols(S, W, t, 1);   // along x
    const float inv = 1.f / (float)N3;
    for (int i = t; i < N2; i += 256) {
        int xr = i / NN, z = i % NN;
        cplx v = S[xr][z];
        base[(size_t)xr * N2 + z] = make_float2(v.x * inv, v.y * inv);
    }
}

// a = f_spec * mul; DFT z, DFT y (no shift) -> out.
// blockIdx.z encodes (ti, term): ti = z>>1, term = z&1. cn volumes per launch.
__global__ __launch_bounds__(256)
void kA_mul(const cplx* __restrict__ spec,
            const float* __restrict__ mul0, const float* __restrict__ mul1,
            cplx* __restrict__ out0, cplx* __restrict__ out1) {
    __shared__ cplx S[NN][NP];
    __shared__ cplx W[NN];
    const int x = blockIdx.x, b = blockIdx.y, t = threadIdx.x;
    const int ti = blockIdx.z >> 1, term = blockIdx.z & 1;
    const float* mulb = term ? mul1 : mul0;
    const float* mul = mulb ? mulb + (size_t)ti * N3 : (const float*)nullptr;
    const cplx* src = spec + (size_t)b * N3 + (size_t)x * N2;
    cplx* out = (term ? out1 : out0) + ((size_t)ti * NB + b) * N3 + (size_t)x * N2;
    for (int i = t; i < N2; i += 256) {
        cplx v = src[i];
        if (mul) { float m = mul[(size_t)x * N2 + i]; v.x *= m; v.y *= m; }
        S[i / NN][i % NN] = v;
    }
    twinit(W, t);
    __syncthreads();
    dft_rows(S, W, t, 0);
    dft_cols(S, W, t, 0);
    for (int i = t; i < N2; i += 256) out[i] = S[i / NN][i % NN];
}

// DFT-x of a and b for TG t-values, accumulate Re(a*b) in registers,
// one atomicAdd per output point.
__global__ __launch_bounds__(256)
void kB_acc(const cplx* __restrict__ va, const cplx* __restrict__ vb,
            float* __restrict__ qacc, int cn) {
    __shared__ cplx SA[NN][NP];
    __shared__ cplx SB[NN][NP];
    __shared__ cplx W[NN];
    const int y = blockIdx.x, b = blockIdx.y, g = blockIdx.z, t = threadIdx.x;
    const int t0g = g * TG;
    const int t1g = (t0g + TG < cn) ? (t0g + TG) : cn;
    twinit(W, t);
    const int kg = t >> 4, zt = t & 15;
    const int k0 = 3*kg, k1 = 3*kg + 1, k2 = 3*kg + 2;
    float qr[3][3];
#pragma unroll
    for (int i = 0; i < 3; ++i)
#pragma unroll
        for (int z = 0; z < 3; ++z) qr[i][z] = 0.f;

    for (int ti = t0g; ti < t1g; ++ti) {
        const cplx* pa = va + ((size_t)ti * NB + b) * N3 + (size_t)y * NN;
        const cplx* pb = vb + ((size_t)ti * NB + b) * N3 + (size_t)y * NN;
        for (int i = t; i < N2; i += 256) {
            int xr = i / NN, z = i % NN;
            SA[xr][z] = pa[(size_t)xr * N2 + z];
            SB[xr][z] = pb[(size_t)xr * N2 + z];
        }
        __syncthreads();
        float Aar[3][3], Aai[3][3], Bar[3][3], Bai[3][3];
#pragma unroll
        for (int i = 0; i < 3; ++i)
#pragma unroll
            for (int z = 0; z < 3; ++z) { Aar[i][z]=0.f; Aai[i][z]=0.f; Bar[i][z]=0.f; Bai[i][z]=0.f; }
        int j0 = 0, j1 = 0, j2 = 0;
        for (int n = 0; n < NN; ++n) {
            cplx a0 = SA[n][3*zt+0], a1 = SA[n][3*zt+1], a2 = SA[n][3*zt+2];
            cplx b0 = SB[n][3*zt+0], b1 = SB[n][3*zt+1], b2 = SB[n][3*zt+2];
            cplx w0 = W[j0], w1 = W[j1], w2 = W[j2];
            CMAC(Aar[0][0], Aai[0][0], a0, w0); CMAC(Aar[0][1], Aai[0][1], a1, w0); CMAC(Aar[0][2], Aai[0][2], a2, w0);
            CMAC(Aar[1][0], Aai[1][0], a0, w1); CMAC(Aar[1][1], Aai[1][1], a1, w1); CMAC(Aar[1][2], Aai[1][2], a2, w1);
            CMAC(Aar[2][0], Aai[2][0], a0, w2); CMAC(Aar[2][1], Aai[2][1], a1, w2); CMAC(Aar[2][2], Aai[2][2], a2, w2);
            CMAC(Bar[0][0], Bai[0][0], b0, w0); CMAC(Bar[0][1], Bai[0][1], b1, w0); CMAC(Bar[0][2], Bai[0][2], b2, w0);
            CMAC(Bar[1][0], Bai[1][0], b0, w1); CMAC(Bar[1][1], Bai[1][1], b1, w1); CMAC(Bar[1][2], Bai[1][2], b2, w1);
            CMAC(Bar[2][0], Bai[2][0], b0, w2); CMAC(Bar[2][1], Bai[2][1], b1, w2); CMAC(Bar[2][2], Bai[2][2], b2, w2);
            j0 += k0; if (j0 >= NN) j0 -= NN;
            j1 += k1; if (j1 >= NN) j1 -= NN;
            j2 += k2; if (j2 >= NN) j2 -= NN;
        }
#pragma unroll
        for (int i = 0; i < 3; ++i)
#pragma unroll
            for (int zi = 0; zi < 3; ++zi)
                qr[i][zi] += Aar[i][zi] * Bar[i][zi] - Aai[i][zi] * Bai[i][zi];
        __syncthreads();
    }
#pragma unroll
    for (int i = 0; i < 3; ++i) {
        int k = 3*kg + i;
#pragma unroll
        for (int zi = 0; zi < 3; ++zi) {
            int z = 3*zt + zi;
            size_t idx = (size_t)b * N3 + (size_t)k * N2 + (size_t)y * NN + z;
            atomicAdd(&qacc[idx], qr[i][zi]);
        }
    }
}

// DFT-x of fl volumes + final combine: dout = scale * (qacc - Re(a*b))
__global__ __launch_bounds__(256)
void kB_fin(const cplx* __restrict__ va, const cplx* __restrict__ vb,
            const float* __restrict__ qacc, const float* __restrict__ kn,
            const int* __restrict__ Mv, float* __restrict__ dout) {
    __shared__ cplx SA[NN][NP];
    __shared__ cplx SB[NN][NP];
    __shared__ cplx W[NN];
    const int y = blockIdx.x, b = blockIdx.y, t = threadIdx.x;
    const cplx* pa = va + (size_t)b * N3 + (size_t)y * NN;
    const cplx* pb = vb + (size_t)b * N3 + (size_t)y * NN;
    for (int i = t; i < N2; i += 256) {
        int xr = i / NN, z = i % NN;
        SA[xr][z] = pa[(size_t)xr * N2 + z];
        SB[xr][z] = pb[(size_t)xr * N2 + z];
    }
    twinit(W, t);
    __syncthreads();
    const int kg = t >> 4, zt = t & 15;
    const int k0 = 3*kg, k1 = 3*kg + 1, k2 = 3*kg + 2;
    float Aar[3][3], Aai[3][3], Bar[3][3], Bai[3][3];
#pragma unroll
    for (int i = 0; i < 3; ++i)
#pragma unroll
        for (int z = 0; z < 3; ++z) { Aar[i][z]=0.f; Aai[i][z]=0.f; Bar[i][z]=0.f; Bai[i][z]=0.f; }
    int j0 = 0, j1 = 0, j2 = 0;
    for (int n = 0; n < NN; ++n) {
        cplx a0 = SA[n][3*zt+0], a1 = SA[n][3*zt+1], a2 = SA[n][3*zt+2];
        cplx b0 = SB[n][3*zt+0], b1 = SB[n][3*zt+1], b2 = SB[n][3*zt+2];
        cplx w0 = W[j0], w1 = W[j1], w2 = W[j2];
        CMAC(Aar[0][0], Aai[0][0], a0, w0); CMAC(Aar[0][1], Aai[0][1], a1, w0); CMAC(Aar[0][2], Aai[0][2], a2, w0);
        CMAC(Aar[1][0], Aai[1][0], a0, w1); CMAC(Aar[1][1], Aai[1][1], a1, w1); CMAC(Aar[1][2], Aai[1][2], a2, w1);
        CMAC(Aar[2][0], Aai[2][0], a0, w2); CMAC(Aar[2][1], Aai[2][1], a1, w2); CMAC(Aar[2][2], Aai[2][2], a2, w2);
        CMAC(Bar[0][0], Bai[0][0], b0, w0); CMAC(Bar[0][1], Bai[0][1], b1, w0); CMAC(Bar[0][2], Bai[0][2], b2, w0);
        CMAC(Bar[1][0], Bai[1][0], b0, w1); CMAC(Bar[1][1], Bai[1][1], b1, w1); CMAC(Bar[1][2], Bai[1][2], b2, w1);
        CMAC(Bar[2][0], Bai[2][0], b0, w2); CMAC(Bar[2][1], Bai[2][1], b1, w2); CMAC(Bar[2][2], Bai[2][2], b2, w2);
        j0 += k0; if (j0 >= NN) j0 -= NN;
        j1 += k1; if (j1 >= NN) j1 -= NN;
        j2 += k2; if (j2 >= NN) j2 -= NN;
    }
    float m = (float)(Mv[0] * Mv[0]);
    float scale = 4.f * 3.14159265358979323846f * 3.14159265358979323846f / (kn[0] * m);
#pragma unroll
    for (int i = 0; i < 3; ++i) {
        int k = 3*kg + i;
#pragma unroll
        for (int zi = 0; zi < 3; ++zi) {
            int z = 3*zt + zi;
            float pr = Aar[i][zi] * Bar[i][zi] - Aai[i][zi] * Bai[i][zi];
            size_t idx = (size_t)b * N3 + (size_t)k * N2 + (size_t)y * NN + z;
            dout[idx] = scale * (qacc[idx] - pr);
        }
    }
}

extern "C" void kernel_launch(void* const* d_in, const int* in_sizes, int n_in,
                              void* d_out, int out_size, void* d_ws, size_t ws_size,
                              hipStream_t stream) {
    const float* f      = (const float*)d_in[0];
    const float* kn     = (const float*)d_in[1];
    const float* phi    = (const float*)d_in[2];
    const float* psi    = (const float*)d_in[3];
    const float* phipsi = (const float*)d_in[4];
    const int*   Mv     = (const int*)d_in[5];
    float* out = (float*)d_out;

    char* w = (char*)d_ws;
    const size_t volcB = (size_t)NB * N3 * sizeof(cplx);   // 7,077,888 B per t-volume-set
    const size_t qaccB = (size_t)NB * N3 * sizeof(float);  // 3,538,944 B
    cplx*  fspec = (cplx*)(w);
    float* qacc  = (float*)(w + volcB);
    char*  pool  = w + volcB + qaccB;

    // how many t fit in scratch simultaneously (constant across calls -> graph-safe)
    size_t avail = (ws_size > volcB + qaccB) ? (ws_size - volcB - qaccB) : 0;
    int chunk = (int)(avail / (2 * volcB));
    if (chunk < 1)  chunk = 1;      // 24.8 MB floor worked last round
    if (chunk > NT) chunk = NT;
    cplx* va = (cplx*)pool;
    cplx* vb = (cplx*)(pool + (size_t)chunk * volcB);

    hipMemsetAsync(qacc, 0, qaccB, stream);

    kA_f<<<dim3(NN, NB), 256, 0, stream>>>(f, fspec);
    kB_f<<<dim3(NN, NB), 256, 0, stream>>>(fspec);

    for (int t0 = 0; t0 < NT; t0 += chunk) {
        int cn = (t0 + chunk <= NT) ? chunk : (NT - t0);
        kA_mul<<<dim3(NN, NB, 2 * cn), 256, 0, stream>>>(
            fspec, phi + (size_t)t0 * N3, psi + (size_t)t0 * N3, va, vb);
        int gz = (cn + TG - 1) / TG;
        kB_acc<<<dim3(NN, NB, gz), 256, 0, stream>>>(va, vb, qacc, cn);
    }

    // fl term: reuse slot 0 of va/vb
    kA_mul<<<dim3(NN, NB, 2), 256, 0, stream>>>(fspec, phipsi, nullptr, va, vb);
    kB_fin<<<dim3(NN, NB), 256, 0, stream>>>(va, vb, qacc, kn, Mv, out);
}

// Round 3
// 449.249 us; speedup vs baseline: 2.4163x; 1.7405x over previous
//
#include <hip/hip_runtime.h>
#include <math.h>

#define NN 48
#define NP 49
#define N2 2304
#define N3 110592
#define NB 8
#define NT 20
#define TG 5     // t-values per kB_acc block

typedef float2 cplx;

// acc += d * w  (complex MAC, 4 FMA)
#define CMAC(AR, AI, D, Wv)                                        \
    AR = fmaf((D).x, (Wv).x, AR); AR = fmaf(-(D).y, (Wv).y, AR);   \
    AI = fmaf((D).x, (Wv).y, AI); AI = fmaf((D).y, (Wv).x, AI);

__device__ __forceinline__ void twinit(cplx* W, int t) {
    if (t < NN) {
        float ang = -6.28318530717958647692f * (float)t / (float)NN;
        float s, c;
        sincosf(ang, &s, &c);
        W[t] = make_float2(c, s);
    }
}

// radix-3 combine: X[j+16m] = sum_r w3^(rm) * (S_r * W48^(rj)),  w3 = e^(-2pi i/3)
__device__ __forceinline__ void radix3_combine(
    float s0r, float s0i, float s1r, float s1i, float s2r, float s2i,
    cplx w1, cplx w2, cplx& X0, cplx& X1, cplx& X2)
{
    float y1r = s1r*w1.x - s1i*w1.y, y1i = s1r*w1.y + s1i*w1.x;
    float y2r = s2r*w2.x - s2i*w2.y, y2i = s2r*w2.y + s2i*w2.x;
    float ar = y1r + y2r, ai = y1i + y2i;
    float br = y1r - y2r, bi = y1i - y2i;
    X0 = make_float2(s0r + ar, s0i + ai);
    float mr = s0r - 0.5f*ar, mi = s0i - 0.5f*ai;
    const float h = 0.86602540378443864676f;   // sqrt(3)/2
    X1 = make_float2(mr + h*bi, mi - h*br);
    X2 = make_float2(mr - h*bi, mi + h*br);
}

// DFT along the SECOND index, radix-3 (48 = 3 x 16).
// thread t: rows 3rg..3rg+2 (rg=t>>4), outputs k = j, j+16, j+32 (j=t&15)
__device__ __forceinline__ void dft_rows(cplx (*S)[NP], const cplx* W, int t, int shift) {
    const int rg = t >> 4;
    const int j  = t & 15;
    float ar[3][3], ai[3][3];   // [row q][sub-DFT r]
#pragma unroll
    for (int q = 0; q < 3; ++q)
#pragma unroll
        for (int r = 0; r < 3; ++r) { ar[q][r] = 0.f; ai[q][r] = 0.f; }
    const int step = 3 * j;
    int tw = 0;
#pragma unroll 4
    for (int n1 = 0; n1 < 16; ++n1) {
        cplx w = W[tw];
#pragma unroll
        for (int q = 0; q < 3; ++q) {
            const cplx* row = S[3*rg + q];
            cplx d0 = row[3*n1+0], d1 = row[3*n1+1], d2 = row[3*n1+2];
            CMAC(ar[q][0], ai[q][0], d0, w);
            CMAC(ar[q][1], ai[q][1], d1, w);
            CMAC(ar[q][2], ai[q][2], d2, w);
        }
        tw += step; if (tw >= NN) tw -= NN;
    }
    cplx w1 = W[j], w2 = W[2*j];
    __syncthreads();
    int k0 = j, k1 = j + 16, k2 = j + 32;
    if (shift) { k0 = (k0+24)%NN; k1 = (k1+24)%NN; k2 = (k2+24)%NN; }
#pragma unroll
    for (int q = 0; q < 3; ++q) {
        cplx X0, X1, X2;
        radix3_combine(ar[q][0],ai[q][0],ar[q][1],ai[q][1],ar[q][2],ai[q][2],w1,w2,X0,X1,X2);
        S[3*rg+q][k0] = X0; S[3*rg+q][k1] = X1; S[3*rg+q][k2] = X2;
    }
    __syncthreads();
}

// DFT along the FIRST index, radix-3.
// thread t: z-cols 3zg..3zg+2 (zg=t&15), outputs k = j, j+16, j+32 (j=t>>4)
__device__ __forceinline__ void dft_cols(cplx (*S)[NP], const cplx* W, int t, int shift) {
    const int zg = t & 15;
    const int j  = t >> 4;
    float ar[3][3], ai[3][3];   // [zi][sub-DFT r]
#pragma unroll
    for (int zi = 0; zi < 3; ++zi)
#pragma unroll
        for (int r = 0; r < 3; ++r) { ar[zi][r] = 0.f; ai[zi][r] = 0.f; }
    const int step = 3 * j;
    int tw = 0;
#pragma unroll 4
    for (int n1 = 0; n1 < 16; ++n1) {
        cplx w = W[tw];
#pragma unroll
        for (int r = 0; r < 3; ++r) {
            const cplx* row = S[3*n1 + r];
            cplx d0 = row[3*zg+0], d1 = row[3*zg+1], d2 = row[3*zg+2];
            CMAC(ar[0][r], ai[0][r], d0, w);
            CMAC(ar[1][r], ai[1][r], d1, w);
            CMAC(ar[2][r], ai[2][r], d2, w);
        }
        tw += step; if (tw >= NN) tw -= NN;
    }
    cplx w1 = W[j], w2 = W[2*j];
    __syncthreads();
    int k0 = j, k1 = j + 16, k2 = j + 32;
    if (shift) { k0 = (k0+24)%NN; k1 = (k1+24)%NN; k2 = (k2+24)%NN; }
#pragma unroll
    for (int zi = 0; zi < 3; ++zi) {
        cplx X0, X1, X2;
        radix3_combine(ar[zi][0],ai[zi][0],ar[zi][1],ai[zi][1],ar[zi][2],ai[zi][2],w1,w2,X0,X1,X2);
        S[k0][3*zg+zi] = X0; S[k1][3*zg+zi] = X1; S[k2][3*zg+zi] = X2;
    }
    __syncthreads();
}

// f (real) -> DFT z, DFT y (both shifted) -> out
__global__ __launch_bounds__(256)
void kA_f(const float* __restrict__ f, cplx* __restrict__ out) {
    __shared__ cplx S[NN][NP];
    __shared__ cplx W[NN];
    const int x = blockIdx.x, b = blockIdx.y, t = threadIdx.x;
    const float* src = f + (size_t)b * N3 + (size_t)x * N2;
    for (int i = t; i < N2; i += 256) S[i / NN][i % NN] = make_float2(src[i], 0.f);
    twinit(W, t);
    __syncthreads();
    dft_rows(S, W, t, 1);   // along z
    dft_cols(S, W, t, 1);   // along y
    cplx* dst = out + (size_t)b * N3 + (size_t)x * N2;
    for (int i = t; i < N2; i += 256) dst[i] = S[i / NN][i % NN];
}

// finalize f_spec: DFT x (shifted), * 1/N3, in place
__global__ __launch_bounds__(256)
void kB_f(cplx* __restrict__ vol) {
    __shared__ cplx S[NN][NP];
    __shared__ cplx W[NN];
    const int y = blockIdx.x, b = blockIdx.y, t = threadIdx.x;
    cplx* base = vol + (size_t)b * N3 + (size_t)y * NN;
    for (int i = t; i < N2; i += 256) { int xr = i / NN, z = i % NN; S[xr][z] = base[(size_t)xr * N2 + z]; }
    twinit(W, t);
    __syncthreads();
    dft_cols(S, W, t, 1);   // along x
    const float inv = 1.f / (float)N3;
    for (int i = t; i < N2; i += 256) {
        int xr = i / NN, z = i % NN;
        cplx v = S[xr][z];
        base[(size_t)xr * N2 + z] = make_float2(v.x * inv, v.y * inv);
    }
}

// a = f_spec * mul; DFT z, DFT y (no shift) -> out.
// blockIdx.z encodes (ti, term): ti = z>>1, term = z&1.
__global__ __launch_bounds__(256)
void kA_mul(const cplx* __restrict__ spec,
            const float* __restrict__ mul0, const float* __restrict__ mul1,
            cplx* __restrict__ out0, cplx* __restrict__ out1) {
    __shared__ cplx S[NN][NP];
    __shared__ cplx W[NN];
    const int x = blockIdx.x, b = blockIdx.y, t = threadIdx.x;
    const int ti = blockIdx.z >> 1, term = blockIdx.z & 1;
    const float* mulb = term ? mul1 : mul0;
    const float* mul = mulb ? mulb + (size_t)ti * N3 : (const float*)nullptr;
    const cplx* src = spec + (size_t)b * N3 + (size_t)x * N2;
    cplx* out = (term ? out1 : out0) + ((size_t)ti * NB + b) * N3 + (size_t)x * N2;
    for (int i = t; i < N2; i += 256) {
        cplx v = src[i];
        if (mul) { float m = mul[(size_t)x * N2 + i]; v.x *= m; v.y *= m; }
        S[i / NN][i % NN] = v;
    }
    twinit(W, t);
    __syncthreads();
    dft_rows(S, W, t, 0);
    dft_cols(S, W, t, 0);
    for (int i = t; i < N2; i += 256) out[i] = S[i / NN][i % NN];
}

// radix-3 DFT-x of a and b for TG t-values, accumulate Re(a*b), atomicAdd out.
__global__ __launch_bounds__(256)
void kB_acc(const cplx* __restrict__ va, const cplx* __restrict__ vb,
            float* __restrict__ qacc, int cn) {
    __shared__ cplx SA[NN][NP];
    __shared__ cplx SB[NN][NP];
    __shared__ cplx W[NN];
    const int y = blockIdx.x, b = blockIdx.y, g = blockIdx.z, t = threadIdx.x;
    const int t0g = g * TG;
    const int t1g = (t0g + TG < cn) ? (t0g + TG) : cn;
    twinit(W, t);
    const int zg = t & 15;
    const int j  = t >> 4;
    const int step = 3 * j;
    float qr[3][3];     // [m][zi], k = j+16m
#pragma unroll
    for (int m = 0; m < 3; ++m)
#pragma unroll
        for (int zi = 0; zi < 3; ++zi) qr[m][zi] = 0.f;

    for (int ti = t0g; ti < t1g; ++ti) {
        const cplx* pa = va + ((size_t)ti * NB + b) * N3 + (size_t)y * NN;
        const cplx* pb = vb + ((size_t)ti * NB + b) * N3 + (size_t)y * NN;
        for (int i = t; i < N2; i += 256) {
            int xr = i / NN, z = i % NN;
            SA[xr][z] = pa[(size_t)xr * N2 + z];
            SB[xr][z] = pb[(size_t)xr * N2 + z];
        }
        __syncthreads();
        float Aar[3][3], Aai[3][3], Bar[3][3], Bai[3][3];  // [zi][r]
#pragma unroll
        for (int zi = 0; zi < 3; ++zi)
#pragma unroll
            for (int r = 0; r < 3; ++r) { Aar[zi][r]=0.f; Aai[zi][r]=0.f; Bar[zi][r]=0.f; Bai[zi][r]=0.f; }
        int tw = 0;
#pragma unroll 4
        for (int n1 = 0; n1 < 16; ++n1) {
            cplx w = W[tw];
#pragma unroll
            for (int r = 0; r < 3; ++r) {
                const cplx* ra = SA[3*n1 + r];
                const cplx* rb = SB[3*n1 + r];
                cplx a0 = ra[3*zg+0], a1 = ra[3*zg+1], a2 = ra[3*zg+2];
                cplx b0 = rb[3*zg+0], b1 = rb[3*zg+1], b2 = rb[3*zg+2];
                CMAC(Aar[0][r], Aai[0][r], a0, w);
                CMAC(Aar[1][r], Aai[1][r], a1, w);
                CMAC(Aar[2][r], Aai[2][r], a2, w);
                CMAC(Bar[0][r], Bai[0][r], b0, w);
                CMAC(Bar[1][r], Bai[1][r], b1, w);
                CMAC(Bar[2][r], Bai[2][r], b2, w);
            }
            tw += step; if (tw >= NN) tw -= NN;
        }
        cplx w1 = W[j], w2 = W[2*j];
#pragma unroll
        for (int zi = 0; zi < 3; ++zi) {
            cplx XA0, XA1, XA2, XB0, XB1, XB2;
            radix3_combine(Aar[zi][0],Aai[zi][0],Aar[zi][1],Aai[zi][1],Aar[zi][2],Aai[zi][2],w1,w2,XA0,XA1,XA2);
            radix3_combine(Bar[zi][0],Bai[zi][0],Bar[zi][1],Bai[zi][1],Bar[zi][2],Bai[zi][2],w1,w2,XB0,XB1,XB2);
            qr[0][zi] += XA0.x*XB0.x - XA0.y*XB0.y;
            qr[1][zi] += XA1.x*XB1.x - XA1.y*XB1.y;
            qr[2][zi] += XA2.x*XB2.x - XA2.y*XB2.y;
        }
        __syncthreads();
    }
#pragma unroll
    for (int m = 0; m < 3; ++m) {
        int k = j + 16*m;
#pragma unroll
        for (int zi = 0; zi < 3; ++zi) {
            int z = 3*zg + zi;
            size_t idx = (size_t)b * N3 + (size_t)k * N2 + (size_t)y * NN + z;
            atomicAdd(&qacc[idx], qr[m][zi]);
        }
    }
}

// radix-3 DFT-x of fl volumes + final combine: dout = scale * (qacc - Re(a*b))
__global__ __launch_bounds__(256)
void kB_fin(const cplx* __restrict__ va, const cplx* __restrict__ vb,
            const float* __restrict__ qacc, const float* __restrict__ kn,
            const int* __restrict__ Mv, float* __restrict__ dout) {
    __shared__ cplx SA[NN][NP];
    __shared__ cplx SB[NN][NP];
    __shared__ cplx W[NN];
    const int y = blockIdx.x, b = blockIdx.y, t = threadIdx.x;
    const cplx* pa = va + (size_t)b * N3 + (size_t)y * NN;
    const cplx* pb = vb + (size_t)b * N3 + (size_t)y * NN;
    for (int i = t; i < N2; i += 256) {
        int xr = i / NN, z = i % NN;
        SA[xr][z] = pa[(size_t)xr * N2 + z];
        SB[xr][z] = pb[(size_t)xr * N2 + z];
    }
    twinit(W, t);
    __syncthreads();
    const int zg = t & 15;
    const int j  = t >> 4;
    const int step = 3 * j;
    float Aar[3][3], Aai[3][3], Bar[3][3], Bai[3][3];
#pragma unroll
    for (int zi = 0; zi < 3; ++zi)
#pragma unroll
        for (int r = 0; r < 3; ++r) { Aar[zi][r]=0.f; Aai[zi][r]=0.f; Bar[zi][r]=0.f; Bai[zi][r]=0.f; }
    int tw = 0;
#pragma unroll 4
    for (int n1 = 0; n1 < 16; ++n1) {
        cplx w = W[tw];
#pragma unroll
        for (int r = 0; r < 3; ++r) {
            const cplx* ra = SA[3*n1 + r];
            const cplx* rb = SB[3*n1 + r];
            cplx a0 = ra[3*zg+0], a1 = ra[3*zg+1], a2 = ra[3*zg+2];
            cplx b0 = rb[3*zg+0], b1 = rb[3*zg+1], b2 = rb[3*zg+2];
            CMAC(Aar[0][r], Aai[0][r], a0, w);
            CMAC(Aar[1][r], Aai[1][r], a1, w);
            CMAC(Aar[2][r], Aai[2][r], a2, w);
            CMAC(Bar[0][r], Bai[0][r], b0, w);
            CMAC(Bar[1][r], Bai[1][r], b1, w);
            CMAC(Bar[2][r], Bai[2][r], b2, w);
        }
        tw += step; if (tw >= NN) tw -= NN;
    }
    float m = (float)(Mv[0] * Mv[0]);
    float scale = 4.f * 3.14159265358979323846f * 3.14159265358979323846f / (kn[0] * m);
    cplx w1 = W[j], w2 = W[2*j];
#pragma unroll
    for (int zi = 0; zi < 3; ++zi) {
        cplx XA0, XA1, XA2, XB0, XB1, XB2;
        radix3_combine(Aar[zi][0],Aai[zi][0],Aar[zi][1],Aai[zi][1],Aar[zi][2],Aai[zi][2],w1,w2,XA0,XA1,XA2);
        radix3_combine(Bar[zi][0],Bai[zi][0],Bar[zi][1],Bai[zi][1],Bar[zi][2],Bai[zi][2],w1,w2,XB0,XB1,XB2);
        int z = 3*zg + zi;
        float p0 = XA0.x*XB0.x - XA0.y*XB0.y;
        float p1 = XA1.x*XB1.x - XA1.y*XB1.y;
        float p2 = XA2.x*XB2.x - XA2.y*XB2.y;
        size_t i0 = (size_t)b * N3 + (size_t)(j      ) * N2 + (size_t)y * NN + z;
        size_t i1 = (size_t)b * N3 + (size_t)(j + 16 ) * N2 + (size_t)y * NN + z;
        size_t i2 = (size_t)b * N3 + (size_t)(j + 32 ) * N2 + (size_t)y * NN + z;
        dout[i0] = scale * (qacc[i0] - p0);
        dout[i1] = scale * (qacc[i1] - p1);
        dout[i2] = scale * (qacc[i2] - p2);
    }
}

extern "C" void kernel_launch(void* const* d_in, const int* in_sizes, int n_in,
                              void* d_out, int out_size, void* d_ws, size_t ws_size,
                              hipStream_t stream) {
    const float* f      = (const float*)d_in[0];
    const float* kn     = (const float*)d_in[1];
    const float* phi    = (const float*)d_in[2];
    const float* psi    = (const float*)d_in[3];
    const float* phipsi = (const float*)d_in[4];
    const int*   Mv     = (const int*)d_in[5];
    float* out = (float*)d_out;

    char* w = (char*)d_ws;
    const size_t volcB = (size_t)NB * N3 * sizeof(cplx);   // 7,077,888 B per t-volume-set
    const size_t qaccB = (size_t)NB * N3 * sizeof(float);  // 3,538,944 B
    cplx*  fspec = (cplx*)(w);
    float* qacc  = (float*)(w + volcB);
    char*  pool  = w + volcB + qaccB;

    size_t avail = (ws_size > volcB + qaccB) ? (ws_size - volcB - qaccB) : 0;
    int chunk = (int)(avail / (2 * volcB));
    if (chunk < 1)  chunk = 1;
    if (chunk > NT) chunk = NT;
    cplx* va = (cplx*)pool;
    cplx* vb = (cplx*)(pool + (size_t)chunk * volcB);

    hipMemsetAsync(qacc, 0, qaccB, stream);

    kA_f<<<dim3(NN, NB), 256, 0, stream>>>(f, fspec);
    kB_f<<<dim3(NN, NB), 256, 0, stream>>>(fspec);

    for (int t0 = 0; t0 < NT; t0 += chunk) {
        int cn = (t0 + chunk <= NT) ? chunk : (NT - t0);
        kA_mul<<<dim3(NN, NB, 2 * cn), 256, 0, stream>>>(
            fspec, phi + (size_t)t0 * N3, psi + (size_t)t0 * N3, va, vb);
        int gz = (cn + TG - 1) / TG;
        kB_acc<<<dim3(NN, NB, gz), 256, 0, stream>>>(va, vb, qacc, cn);
    }

    kA_mul<<<dim3(NN, NB, 2), 256, 0, stream>>>(fspec, phipsi, nullptr, va, vb);
    kB_fin<<<dim3(NN, NB), 256, 0, stream>>>(va, vb, qacc, kn, Mv, out);
}

// Round 4
// 306.073 us; speedup vs baseline: 3.5467x; 1.4678x over previous
//
#include <hip/hip_runtime.h>
#include <math.h>

#define NN 48
#define NP 49
#define N2 2304
#define N3 110592
#define NB 8
#define NT 20
#define NH 25      // Hermitian half: slabs 0..24
#define NSL 7      // t-slices in kB_all

typedef float2 cplx;

// acc += d * w  (complex MAC, 4 FMA)
#define CMAC(AR, AI, D, Wv)                                        \
    AR = fmaf((D).x, (Wv).x, AR); AR = fmaf(-(D).y, (Wv).y, AR);   \
    AI = fmaf((D).x, (Wv).y, AI); AI = fmaf((D).y, (Wv).x, AI);

__device__ __forceinline__ void twinit(cplx* W, int t) {
    if (t < NN) {
        float ang = -6.28318530717958647692f * (float)t / (float)NN;
        float s, c;
        sincosf(ang, &s, &c);
        W[t] = make_float2(c, s);
    }
}

// radix-3 combine: X[j+16m] = sum_r w3^(rm) * (S_r * W48^(rj))
__device__ __forceinline__ void radix3_combine(
    float s0r, float s0i, float s1r, float s1i, float s2r, float s2i,
    cplx w1, cplx w2, cplx& X0, cplx& X1, cplx& X2)
{
    float y1r = s1r*w1.x - s1i*w1.y, y1i = s1r*w1.y + s1i*w1.x;
    float y2r = s2r*w2.x - s2i*w2.y, y2i = s2r*w2.y + s2i*w2.x;
    float ar = y1r + y2r, ai = y1i + y2i;
    float br = y1r - y2r, bi = y1i - y2i;
    X0 = make_float2(s0r + ar, s0i + ai);
    float mr = s0r - 0.5f*ar, mi = s0i - 0.5f*ai;
    const float h = 0.86602540378443864676f;
    X1 = make_float2(mr + h*bi, mi - h*br);
    X2 = make_float2(mr - h*bi, mi + h*br);
}

// DFT along SECOND index, radix-3 (48 = 3 x 16)
__device__ __forceinline__ void dft_rows(cplx (*S)[NP], const cplx* W, int t, int shift) {
    const int rg = t >> 4;
    const int j  = t & 15;
    float ar[3][3], ai[3][3];
#pragma unroll
    for (int q = 0; q < 3; ++q)
#pragma unroll
        for (int r = 0; r < 3; ++r) { ar[q][r] = 0.f; ai[q][r] = 0.f; }
    const int step = 3 * j;
    int tw = 0;
#pragma unroll 4
    for (int n1 = 0; n1 < 16; ++n1) {
        cplx w = W[tw];
#pragma unroll
        for (int q = 0; q < 3; ++q) {
            const cplx* row = S[3*rg + q];
            cplx d0 = row[3*n1+0], d1 = row[3*n1+1], d2 = row[3*n1+2];
            CMAC(ar[q][0], ai[q][0], d0, w);
            CMAC(ar[q][1], ai[q][1], d1, w);
            CMAC(ar[q][2], ai[q][2], d2, w);
        }
        tw += step; if (tw >= NN) tw -= NN;
    }
    cplx w1 = W[j], w2 = W[2*j];
    __syncthreads();
    int k0 = j, k1 = j + 16, k2 = j + 32;
    if (shift) { k0 = (k0+24)%NN; k1 = (k1+24)%NN; k2 = (k2+24)%NN; }
#pragma unroll
    for (int q = 0; q < 3; ++q) {
        cplx X0, X1, X2;
        radix3_combine(ar[q][0],ai[q][0],ar[q][1],ai[q][1],ar[q][2],ai[q][2],w1,w2,X0,X1,X2);
        S[3*rg+q][k0] = X0; S[3*rg+q][k1] = X1; S[3*rg+q][k2] = X2;
    }
    __syncthreads();
}

// DFT along FIRST index, radix-3
__device__ __forceinline__ void dft_cols(cplx (*S)[NP], const cplx* W, int t, int shift) {
    const int zg = t & 15;
    const int j  = t >> 4;
    float ar[3][3], ai[3][3];
#pragma unroll
    for (int zi = 0; zi < 3; ++zi)
#pragma unroll
        for (int r = 0; r < 3; ++r) { ar[zi][r] = 0.f; ai[zi][r] = 0.f; }
    const int step = 3 * j;
    int tw = 0;
#pragma unroll 4
    for (int n1 = 0; n1 < 16; ++n1) {
        cplx w = W[tw];
#pragma unroll
        for (int r = 0; r < 3; ++r) {
            const cplx* row = S[3*n1 + r];
            cplx d0 = row[3*zg+0], d1 = row[3*zg+1], d2 = row[3*zg+2];
            CMAC(ar[0][r], ai[0][r], d0, w);
            CMAC(ar[1][r], ai[1][r], d1, w);
            CMAC(ar[2][r], ai[2][r], d2, w);
        }
        tw += step; if (tw >= NN) tw -= NN;
    }
    cplx w1 = W[j], w2 = W[2*j];
    __syncthreads();
    int k0 = j, k1 = j + 16, k2 = j + 32;
    if (shift) { k0 = (k0+24)%NN; k1 = (k1+24)%NN; k2 = (k2+24)%NN; }
#pragma unroll
    for (int zi = 0; zi < 3; ++zi) {
        cplx X0, X1, X2;
        radix3_combine(ar[zi][0],ai[zi][0],ar[zi][1],ai[zi][1],ar[zi][2],ai[zi][2],w1,w2,X0,X1,X2);
        S[k0][3*zg+zi] = X0; S[k1][3*zg+zi] = X1; S[k2][3*zg+zi] = X2;
    }
    __syncthreads();
}

// f (real) -> DFT z, DFT y (both shifted)
__global__ __launch_bounds__(256)
void kA_f(const float* __restrict__ f, cplx* __restrict__ out) {
    __shared__ cplx S[NN][NP];
    __shared__ cplx W[NN];
    const int x = blockIdx.x, b = blockIdx.y, t = threadIdx.x;
    const float* src = f + (size_t)b * N3 + (size_t)x * N2;
    for (int i = t; i < N2; i += 256) S[i / NN][i % NN] = make_float2(src[i], 0.f);
    twinit(W, t);
    __syncthreads();
    dft_rows(S, W, t, 1);
    dft_cols(S, W, t, 1);
    cplx* dst = out + (size_t)b * N3 + (size_t)x * N2;
    for (int i = t; i < N2; i += 256) dst[i] = S[i / NN][i % NN];
}

// finalize f_spec: DFT x (shifted), * 1/N3, in place
__global__ __launch_bounds__(256)
void kB_f(cplx* __restrict__ vol) {
    __shared__ cplx S[NN][NP];
    __shared__ cplx W[NN];
    const int y = blockIdx.x, b = blockIdx.y, t = threadIdx.x;
    cplx* base = vol + (size_t)b * N3 + (size_t)y * NN;
    for (int i = t; i < N2; i += 256) { int xr = i / NN, z = i % NN; S[xr][z] = base[(size_t)xr * N2 + z]; }
    twinit(W, t);
    __syncthreads();
    dft_cols(S, W, t, 1);
    const float inv = 1.f / (float)N3;
    for (int i = t; i < N2; i += 256) {
        int xr = i / NN, z = i % NN;
        cplx v = S[xr][z];
        base[(size_t)xr * N2 + z] = make_float2(v.x * inv, v.y * inv);
    }
}

// a = f_spec * mul; DFT z, DFT y (no shift) -> Hermitian-half slabs ix=0..24.
// blockIdx.z = 2*lt + term; global ti = t0+lt. ti==NT is the fl pair
// (mul0 = phipsi, mul1 = identity).
__global__ __launch_bounds__(256)
void kA_mul(const cplx* __restrict__ spec,
            const float* __restrict__ phi, const float* __restrict__ psi,
            const float* __restrict__ phipsi,
            cplx* __restrict__ va, cplx* __restrict__ vb, int t0) {
    __shared__ cplx S[NN][NP];
    __shared__ cplx W[NN];
    const int ix = blockIdx.x, b = blockIdx.y, t = threadIdx.x;
    const int lt = blockIdx.z >> 1, term = blockIdx.z & 1;
    const int ti = t0 + lt;
    const float* mul;
    if (ti < NT) mul = (term ? psi : phi) + (size_t)ti * N3 + (size_t)ix * N2;
    else         mul = term ? (const float*)nullptr : (phipsi + (size_t)ix * N2);
    const cplx* src = spec + (size_t)b * N3 + (size_t)ix * N2;
    cplx* out = (term ? vb : va) + ((size_t)(lt * NB + b) * NH + ix) * N2;
    for (int i = t; i < N2; i += 256) {
        cplx v = src[i];
        if (mul) { float m = mul[i]; v.x *= m; v.y *= m; }
        S[i / NN][i % NN] = v;
    }
    twinit(W, t);
    __syncthreads();
    dft_rows(S, W, t, 0);
    dft_cols(S, W, t, 0);
    for (int i = t; i < N2; i += 256) out[i] = S[i / NN][i % NN];
}

// Real-valued x-DFT via Hermitian symmetry + product + t-accumulate.
// A-hat[j] = A[0] + (-1)^j A[24] + 2*sum_{n=1}^{23} Re(A[n] * W48^{n j}); all real.
// qr += (ti==NT ? -1 : +1) * A-hat * B-hat; atomicAdd(out, scale*qr).
__global__ __launch_bounds__(256)
void kB_all(const cplx* __restrict__ va, const cplx* __restrict__ vb,
            float* __restrict__ out, const float* __restrict__ kn,
            const int* __restrict__ Mv, int t0, int cn) {
    __shared__ cplx SA[NH][NP];
    __shared__ cplx SB[NH][NP];
    __shared__ cplx W[NN];
    const int y = blockIdx.x, b = blockIdx.y, s = blockIdx.z, t = threadIdx.x;
    twinit(W, t);
    const int zg = t & 15, jg = t >> 4;
    float qr[3][3];   // [m][zi], output j = jg + 16m, z = 3zg + zi
#pragma unroll
    for (int m = 0; m < 3; ++m)
#pragma unroll
        for (int zi = 0; zi < 3; ++zi) qr[m][zi] = 0.f;

    for (int lt = s; lt < cn; lt += NSL) {
        const int ti = t0 + lt;
        const cplx* pa = va + (size_t)(lt * NB + b) * NH * N2 + (size_t)y * NN;
        const cplx* pb = vb + (size_t)(lt * NB + b) * NH * N2 + (size_t)y * NN;
        for (int i = t; i < NH * NN; i += 256) {
            int n = i / NN, z = i % NN;
            SA[n][z] = pa[(size_t)n * N2 + z];
            SB[n][z] = pb[(size_t)n * N2 + z];
        }
        __syncthreads();
        float sa[3][3], sb[3][3];
#pragma unroll
        for (int m = 0; m < 3; ++m)
#pragma unroll
            for (int zi = 0; zi < 3; ++zi) { sa[m][zi] = 0.f; sb[m][zi] = 0.f; }
        int m0 = jg, m1 = jg + 16, m2 = jg + 32;
        const int s0 = jg, s1 = jg + 16, s2 = jg + 32;
        for (int n = 1; n <= 23; ++n) {
            cplx w0 = W[m0], w1 = W[m1], w2 = W[m2];
#pragma unroll
            for (int zi = 0; zi < 3; ++zi) {
                cplx A = SA[n][3*zg+zi];
                cplx B = SB[n][3*zg+zi];
                sa[0][zi] = fmaf(A.x, w0.x, sa[0][zi]); sa[0][zi] = fmaf(-A.y, w0.y, sa[0][zi]);
                sa[1][zi] = fmaf(A.x, w1.x, sa[1][zi]); sa[1][zi] = fmaf(-A.y, w1.y, sa[1][zi]);
                sa[2][zi] = fmaf(A.x, w2.x, sa[2][zi]); sa[2][zi] = fmaf(-A.y, w2.y, sa[2][zi]);
                sb[0][zi] = fmaf(B.x, w0.x, sb[0][zi]); sb[0][zi] = fmaf(-B.y, w0.y, sb[0][zi]);
                sb[1][zi] = fmaf(B.x, w1.x, sb[1][zi]); sb[1][zi] = fmaf(-B.y, w1.y, sb[1][zi]);
                sb[2][zi] = fmaf(B.x, w2.x, sb[2][zi]); sb[2][zi] = fmaf(-B.y, w2.y, sb[2][zi]);
            }
            m0 += s0; if (m0 >= NN) m0 -= NN;
            m1 += s1; if (m1 >= NN) m1 -= NN;
            m2 += s2; if (m2 >= NN) m2 -= NN;
        }
        const float sgn = (jg & 1) ? -1.f : 1.f;
        const float wgt = (ti == NT) ? -1.f : 1.f;
#pragma unroll
        for (int zi = 0; zi < 3; ++zi) {
            float e0a  = SA[0][3*zg+zi].x,  e24a = SA[24][3*zg+zi].x;
            float e0b  = SB[0][3*zg+zi].x,  e24b = SB[24][3*zg+zi].x;
            float basea = e0a + sgn * e24a;
            float baseb = e0b + sgn * e24b;
#pragma unroll
            for (int m = 0; m < 3; ++m) {
                float Ah = basea + 2.f * sa[m][zi];
                float Bh = baseb + 2.f * sb[m][zi];
                qr[m][zi] += wgt * Ah * Bh;
            }
        }
        __syncthreads();
    }
    float mf = (float)(Mv[0] * Mv[0]);
    float scale = 4.f * 3.14159265358979323846f * 3.14159265358979323846f / (kn[0] * mf);
#pragma unroll
    for (int m = 0; m < 3; ++m) {
        int j = jg + 16 * m;
#pragma unroll
        for (int zi = 0; zi < 3; ++zi) {
            int z = 3 * zg + zi;
            size_t idx = (size_t)b * N3 + (size_t)j * N2 + (size_t)y * NN + z;
            atomicAdd(&out[idx], scale * qr[m][zi]);
        }
    }
}

extern "C" void kernel_launch(void* const* d_in, const int* in_sizes, int n_in,
                              void* d_out, int out_size, void* d_ws, size_t ws_size,
                              hipStream_t stream) {
    const float* f      = (const float*)d_in[0];
    const float* kn     = (const float*)d_in[1];
    const float* phi    = (const float*)d_in[2];
    const float* psi    = (const float*)d_in[3];
    const float* phipsi = (const float*)d_in[4];
    const int*   Mv     = (const int*)d_in[5];
    float* out = (float*)d_out;

    char* w = (char*)d_ws;
    const size_t fspecB = (size_t)NB * N3 * sizeof(cplx);         // 7,077,888
    const size_t perTB  = (size_t)NB * NH * N2 * sizeof(cplx);    // 3,686,400 per term
    cplx* fspec = (cplx*)w;
    char* pool  = w + fspecB;

    const int NTOT = NT + 1;   // 20 fg terms + 1 fl term
    size_t avail = (ws_size > fspecB) ? (ws_size - fspecB) : 0;
    int chunk = (int)(avail / (2 * perTB));
    if (chunk < 1)    chunk = 1;
    if (chunk > NTOT) chunk = NTOT;
    cplx* va = (cplx*)pool;
    cplx* vb = (cplx*)(pool + (size_t)chunk * perTB);

    hipMemsetAsync(out, 0, (size_t)NB * N3 * sizeof(float), stream);

    kA_f<<<dim3(NN, NB), 256, 0, stream>>>(f, fspec);
    kB_f<<<dim3(NN, NB), 256, 0, stream>>>(fspec);

    for (int t0 = 0; t0 < NTOT; t0 += chunk) {
        int cn = (t0 + chunk <= NTOT) ? chunk : (NTOT - t0);
        kA_mul<<<dim3(NH, NB, 2 * cn), 256, 0, stream>>>(
            fspec, phi, psi, phipsi, va, vb, t0);
        kB_all<<<dim3(NN, NB, NSL), 256, 0, stream>>>(va, vb, out, kn, Mv, t0, cn);
    }
}

// Round 5
// 290.176 us; speedup vs baseline: 3.7410x; 1.0548x over previous
//
#include <hip/hip_runtime.h>
#include <math.h>

#define NN 48
#define NP 49
#define N2 2304
#define N3 110592
#define NB 8
#define NT 20
#define NH 25      // Hermitian half: slabs 0..24
#define NSL 7      // t-slices in kB_all

typedef float2 cplx;

// acc += d * w  (complex MAC, 4 FMA)
#define CMAC(AR, AI, D, Wv)                                        \
    AR = fmaf((D).x, (Wv).x, AR); AR = fmaf(-(D).y, (Wv).y, AR);   \
    AI = fmaf((D).x, (Wv).y, AI); AI = fmaf((D).y, (Wv).x, AI);

// dual complex MAC on float4 (A in .xy, B in .zw), 8 FMA, one twiddle
#define CMAC4(AC, D, Wv)                                             \
    (AC).x = fmaf((D).x, (Wv).x, (AC).x); (AC).x = fmaf(-(D).y, (Wv).y, (AC).x); \
    (AC).y = fmaf((D).x, (Wv).y, (AC).y); (AC).y = fmaf((D).y, (Wv).x, (AC).y); \
    (AC).z = fmaf((D).z, (Wv).x, (AC).z); (AC).z = fmaf(-(D).w, (Wv).y, (AC).z); \
    (AC).w = fmaf((D).z, (Wv).y, (AC).w); (AC).w = fmaf((D).w, (Wv).x, (AC).w);

__device__ __forceinline__ void twinit(cplx* W, int t) {
    if (t < NN) {
        float ang = -6.28318530717958647692f * (float)t / (float)NN;
        float s, c;
        sincosf(ang, &s, &c);
        W[t] = make_float2(c, s);
    }
}

// radix-3 combine (complex): X[j+16m] = sum_r w3^(rm) * (S_r * W48^(rj))
__device__ __forceinline__ void radix3_combine(
    float s0r, float s0i, float s1r, float s1i, float s2r, float s2i,
    cplx w1, cplx w2, cplx& X0, cplx& X1, cplx& X2)
{
    float y1r = s1r*w1.x - s1i*w1.y, y1i = s1r*w1.y + s1i*w1.x;
    float y2r = s2r*w2.x - s2i*w2.y, y2i = s2r*w2.y + s2i*w2.x;
    float ar = y1r + y2r, ai = y1i + y2i;
    float br = y1r - y2r, bi = y1i - y2i;
    X0 = make_float2(s0r + ar, s0i + ai);
    float mr = s0r - 0.5f*ar, mi = s0i - 0.5f*ai;
    const float h = 0.86602540378443864676f;
    X1 = make_float2(mr + h*bi, mi - h*br);
    X2 = make_float2(mr - h*bi, mi + h*br);
}

// radix-3 combine on dual-complex float4
__device__ __forceinline__ void radix3_combine4(
    float4 s0, float4 s1, float4 s2, cplx w1, cplx w2,
    float4& X0, float4& X1, float4& X2)
{
    cplx a0, a1, a2, b0, b1, b2;
    radix3_combine(s0.x, s0.y, s1.x, s1.y, s2.x, s2.y, w1, w2, a0, a1, a2);
    radix3_combine(s0.z, s0.w, s1.z, s1.w, s2.z, s2.w, w1, w2, b0, b1, b2);
    X0 = make_float4(a0.x, a0.y, b0.x, b0.y);
    X1 = make_float4(a1.x, a1.y, b1.x, b1.y);
    X2 = make_float4(a2.x, a2.y, b2.x, b2.y);
}

// ---------- float2 (cplx) radix-3 DFT helpers (kA_f / kB_f) ----------
__device__ __forceinline__ void dft_rows(cplx (*S)[NP], const cplx* W, int t, int shift) {
    const int rg = t >> 4;
    const int j  = t & 15;
    float ar[3][3], ai[3][3];
#pragma unroll
    for (int q = 0; q < 3; ++q)
#pragma unroll
        for (int r = 0; r < 3; ++r) { ar[q][r] = 0.f; ai[q][r] = 0.f; }
    const int step = 3 * j;
    int tw = 0;
#pragma unroll 4
    for (int n1 = 0; n1 < 16; ++n1) {
        cplx w = W[tw];
#pragma unroll
        for (int q = 0; q < 3; ++q) {
            const cplx* row = S[3*rg + q];
            cplx d0 = row[3*n1+0], d1 = row[3*n1+1], d2 = row[3*n1+2];
            CMAC(ar[q][0], ai[q][0], d0, w);
            CMAC(ar[q][1], ai[q][1], d1, w);
            CMAC(ar[q][2], ai[q][2], d2, w);
        }
        tw += step; if (tw >= NN) tw -= NN;
    }
    cplx w1 = W[j], w2 = W[2*j];
    __syncthreads();
    int k0 = j, k1 = j + 16, k2 = j + 32;
    if (shift) { k0 = (k0+24)%NN; k1 = (k1+24)%NN; k2 = (k2+24)%NN; }
#pragma unroll
    for (int q = 0; q < 3; ++q) {
        cplx X0, X1, X2;
        radix3_combine(ar[q][0],ai[q][0],ar[q][1],ai[q][1],ar[q][2],ai[q][2],w1,w2,X0,X1,X2);
        S[3*rg+q][k0] = X0; S[3*rg+q][k1] = X1; S[3*rg+q][k2] = X2;
    }
    __syncthreads();
}

__device__ __forceinline__ void dft_cols(cplx (*S)[NP], const cplx* W, int t, int shift) {
    const int zg = t & 15;
    const int j  = t >> 4;
    float ar[3][3], ai[3][3];
#pragma unroll
    for (int zi = 0; zi < 3; ++zi)
#pragma unroll
        for (int r = 0; r < 3; ++r) { ar[zi][r] = 0.f; ai[zi][r] = 0.f; }
    const int step = 3 * j;
    int tw = 0;
#pragma unroll 4
    for (int n1 = 0; n1 < 16; ++n1) {
        cplx w = W[tw];
#pragma unroll
        for (int r = 0; r < 3; ++r) {
            const cplx* row = S[3*n1 + r];
            cplx d0 = row[3*zg+0], d1 = row[3*zg+1], d2 = row[3*zg+2];
            CMAC(ar[0][r], ai[0][r], d0, w);
            CMAC(ar[1][r], ai[1][r], d1, w);
            CMAC(ar[2][r], ai[2][r], d2, w);
        }
        tw += step; if (tw >= NN) tw -= NN;
    }
    cplx w1 = W[j], w2 = W[2*j];
    __syncthreads();
    int k0 = j, k1 = j + 16, k2 = j + 32;
    if (shift) { k0 = (k0+24)%NN; k1 = (k1+24)%NN; k2 = (k2+24)%NN; }
#pragma unroll
    for (int zi = 0; zi < 3; ++zi) {
        cplx X0, X1, X2;
        radix3_combine(ar[zi][0],ai[zi][0],ar[zi][1],ai[zi][1],ar[zi][2],ai[zi][2],w1,w2,X0,X1,X2);
        S[k0][3*zg+zi] = X0; S[k1][3*zg+zi] = X1; S[k2][3*zg+zi] = X2;
    }
    __syncthreads();
}

// ---------- float4 (dual complex) radix-3 DFT helpers (kAB) ----------
__device__ __forceinline__ void dft_rows4(float4 (*S)[NP], const cplx* W, int t) {
    const int rg = t >> 4;
    const int j  = t & 15;
    float4 acc[3][3];
#pragma unroll
    for (int q = 0; q < 3; ++q)
#pragma unroll
        for (int r = 0; r < 3; ++r) acc[q][r] = make_float4(0.f,0.f,0.f,0.f);
    const int step = 3 * j;
    int tw = 0;
    const float4* r0 = S[3*rg + 0];
    const float4* r1 = S[3*rg + 1];
    const float4* r2 = S[3*rg + 2];
#pragma unroll 4
    for (int n1 = 0; n1 < 16; ++n1) {
        cplx w = W[tw];
        float4 d00 = r0[3*n1+0], d01 = r0[3*n1+1], d02 = r0[3*n1+2];
        float4 d10 = r1[3*n1+0], d11 = r1[3*n1+1], d12 = r1[3*n1+2];
        float4 d20 = r2[3*n1+0], d21 = r2[3*n1+1], d22 = r2[3*n1+2];
        CMAC4(acc[0][0], d00, w); CMAC4(acc[0][1], d01, w); CMAC4(acc[0][2], d02, w);
        CMAC4(acc[1][0], d10, w); CMAC4(acc[1][1], d11, w); CMAC4(acc[1][2], d12, w);
        CMAC4(acc[2][0], d20, w); CMAC4(acc[2][1], d21, w); CMAC4(acc[2][2], d22, w);
        tw += step; if (tw >= NN) tw -= NN;
    }
    cplx w1 = W[j], w2 = W[2*j];
    __syncthreads();
#pragma unroll
    for (int q = 0; q < 3; ++q) {
        float4 X0, X1, X2;
        radix3_combine4(acc[q][0], acc[q][1], acc[q][2], w1, w2, X0, X1, X2);
        S[3*rg+q][j] = X0; S[3*rg+q][j+16] = X1; S[3*rg+q][j+32] = X2;
    }
    __syncthreads();
}

__device__ __forceinline__ void dft_cols4(float4 (*S)[NP], const cplx* W, int t) {
    const int zg = t & 15;
    const int j  = t >> 4;
    float4 acc[3][3];   // [zi][r]
#pragma unroll
    for (int zi = 0; zi < 3; ++zi)
#pragma unroll
        for (int r = 0; r < 3; ++r) acc[zi][r] = make_float4(0.f,0.f,0.f,0.f);
    const int step = 3 * j;
    int tw = 0;
#pragma unroll 4
    for (int n1 = 0; n1 < 16; ++n1) {
        cplx w = W[tw];
#pragma unroll
        for (int r = 0; r < 3; ++r) {
            const float4* row = S[3*n1 + r];
            float4 d0 = row[3*zg+0], d1 = row[3*zg+1], d2 = row[3*zg+2];
            CMAC4(acc[0][r], d0, w);
            CMAC4(acc[1][r], d1, w);
            CMAC4(acc[2][r], d2, w);
        }
        tw += step; if (tw >= NN) tw -= NN;
    }
    cplx w1 = W[j], w2 = W[2*j];
    __syncthreads();
#pragma unroll
    for (int zi = 0; zi < 3; ++zi) {
        float4 X0, X1, X2;
        radix3_combine4(acc[zi][0], acc[zi][1], acc[zi][2], w1, w2, X0, X1, X2);
        S[j][3*zg+zi] = X0; S[j+16][3*zg+zi] = X1; S[j+32][3*zg+zi] = X2;
    }
    __syncthreads();
}

// f (real) -> DFT z, DFT y (both shifted)
__global__ __launch_bounds__(256)
void kA_f(const float* __restrict__ f, cplx* __restrict__ out) {
    __shared__ cplx S[NN][NP];
    __shared__ cplx W[NN];
    const int x = blockIdx.x, b = blockIdx.y, t = threadIdx.x;
    const float* src = f + (size_t)b * N3 + (size_t)x * N2;
    for (int i = t; i < N2; i += 256) S[i / NN][i % NN] = make_float2(src[i], 0.f);
    twinit(W, t);
    __syncthreads();
    dft_rows(S, W, t, 1);
    dft_cols(S, W, t, 1);
    cplx* dst = out + (size_t)b * N3 + (size_t)x * N2;
    for (int i = t; i < N2; i += 256) dst[i] = S[i / NN][i % NN];
}

// finalize f_spec: DFT x (shifted), * 1/N3, in place
__global__ __launch_bounds__(256)
void kB_f(cplx* __restrict__ vol) {
    __shared__ cplx S[NN][NP];
    __shared__ cplx W[NN];
    const int y = blockIdx.x, b = blockIdx.y, t = threadIdx.x;
    cplx* base = vol + (size_t)b * N3 + (size_t)y * NN;
    for (int i = t; i < N2; i += 256) { int xr = i / NN, z = i % NN; S[xr][z] = base[(size_t)xr * N2 + z]; }
    twinit(W, t);
    __syncthreads();
    dft_cols(S, W, t, 1);
    const float inv = 1.f / (float)N3;
    for (int i = t; i < N2; i += 256) {
        int xr = i / NN, z = i % NN;
        cplx v = S[xr][z];
        base[(size_t)xr * N2 + z] = make_float2(v.x * inv, v.y * inv);
    }
}

// Fused A-pass: one block computes BOTH va = F2(spec*phi) and vb = F2(spec*psi)
// as a dual-complex float4 stream. blockIdx.z = lt; global ti = t0+lt.
// ti==NT -> fl pair (phipsi, identity).
__global__ __launch_bounds__(256)
void kAB(const cplx* __restrict__ spec,
         const float* __restrict__ phi, const float* __restrict__ psi,
         const float* __restrict__ phipsi,
         float4* __restrict__ vab, int t0) {
    __shared__ float4 S[NN][NP];
    __shared__ cplx W[NN];
    const int ix = blockIdx.x, b = blockIdx.y, lt = blockIdx.z, t = threadIdx.x;
    const int ti = t0 + lt;
    const cplx* src = spec + (size_t)b * N3 + (size_t)ix * N2;
    const float* mp;
    const float* mq;
    if (ti < NT) { mp = phi + (size_t)ti * N3 + (size_t)ix * N2; mq = psi + (size_t)ti * N3 + (size_t)ix * N2; }
    else         { mp = phipsi + (size_t)ix * N2;               mq = (const float*)nullptr; }
    for (int i = t; i < N2; i += 256) {
        cplx v = src[i];
        float p = mp[i];
        float q = mq ? mq[i] : 1.f;
        S[i / NN][i % NN] = make_float4(v.x * p, v.y * p, v.x * q, v.y * q);
    }
    twinit(W, t);
    __syncthreads();
    dft_rows4(S, W, t);
    dft_cols4(S, W, t);
    float4* out = vab + ((size_t)(lt * NB + b) * NH + ix) * N2;
    for (int i = t; i < N2; i += 256) out[i] = S[i / NN][i % NN];
}

// Real-valued x-DFT via Hermitian symmetry + product + t-accumulate.
// Ah[j] = A[0] + (-1)^j A[24] + 2*sum_{n=1}^{23} Re(A[n] W48^{nj}).
__global__ __launch_bounds__(256)
void kB_all(const float4* __restrict__ vab,
            float* __restrict__ out, const float* __restrict__ kn,
            const int* __restrict__ Mv, int t0, int cn) {
    __shared__ float4 SAB[NH][NP];
    __shared__ cplx W[NN];
    const int y = blockIdx.x, b = blockIdx.y, s = blockIdx.z, t = threadIdx.x;
    twinit(W, t);
    const int zg = t & 15, jg = t >> 4;
    float qr[3][3];   // [m][zi]
#pragma unroll
    for (int m = 0; m < 3; ++m)
#pragma unroll
        for (int zi = 0; zi < 3; ++zi) qr[m][zi] = 0.f;

    for (int lt = s; lt < cn; lt += NSL) {
        const int ti = t0 + lt;
        const float4* pa = vab + (size_t)(lt * NB + b) * NH * N2 + (size_t)y * NN;
        for (int i = t; i < NH * NN; i += 256) {
            int n = i / NN, z = i % NN;
            SAB[n][z] = pa[(size_t)n * N2 + z];
        }
        __syncthreads();
        float sa[3][3], sb[3][3];   // [m][zi]
#pragma unroll
        for (int m = 0; m < 3; ++m)
#pragma unroll
            for (int zi = 0; zi < 3; ++zi) { sa[m][zi] = 0.f; sb[m][zi] = 0.f; }
        int m0 = jg, m1 = jg + 16, m2 = jg + 32;
        const int s0 = jg, s1 = jg + 16, s2 = jg + 32;
        for (int n = 1; n <= 23; ++n) {
            cplx w0 = W[m0], w1 = W[m1], w2 = W[m2];
#pragma unroll
            for (int zi = 0; zi < 3; ++zi) {
                float4 d = SAB[n][3*zg+zi];
                sa[0][zi] = fmaf(d.x, w0.x, sa[0][zi]); sa[0][zi] = fmaf(-d.y, w0.y, sa[0][zi]);
                sa[1][zi] = fmaf(d.x, w1.x, sa[1][zi]); sa[1][zi] = fmaf(-d.y, w1.y, sa[1][zi]);
                sa[2][zi] = fmaf(d.x, w2.x, sa[2][zi]); sa[2][zi] = fmaf(-d.y, w2.y, sa[2][zi]);
                sb[0][zi] = fmaf(d.z, w0.x, sb[0][zi]); sb[0][zi] = fmaf(-d.w, w0.y, sb[0][zi]);
                sb[1][zi] = fmaf(d.z, w1.x, sb[1][zi]); sb[1][zi] = fmaf(-d.w, w1.y, sb[1][zi]);
                sb[2][zi] = fmaf(d.z, w2.x, sb[2][zi]); sb[2][zi] = fmaf(-d.w, w2.y, sb[2][zi]);
            }
            m0 += s0; if (m0 >= NN) m0 -= NN;
            m1 += s1; if (m1 >= NN) m1 -= NN;
            m2 += s2; if (m2 >= NN) m2 -= NN;
        }
        const float sgn = (jg & 1) ? -1.f : 1.f;
        const float wgt = (ti == NT) ? -1.f : 1.f;
#pragma unroll
        for (int zi = 0; zi < 3; ++zi) {
            float4 e0  = SAB[0][3*zg+zi];
            float4 e24 = SAB[24][3*zg+zi];
            float basea = e0.x + sgn * e24.x;
            float baseb = e0.z + sgn * e24.z;
#pragma unroll
            for (int m = 0; m < 3; ++m) {
                float Ah = basea + 2.f * sa[m][zi];
                float Bh = baseb + 2.f * sb[m][zi];
                qr[m][zi] += wgt * Ah * Bh;
            }
        }
        __syncthreads();
    }
    float mf = (float)(Mv[0] * Mv[0]);
    float scale = 4.f * 3.14159265358979323846f * 3.14159265358979323846f / (kn[0] * mf);
#pragma unroll
    for (int m = 0; m < 3; ++m) {
        int j = jg + 16 * m;
#pragma unroll
        for (int zi = 0; zi < 3; ++zi) {
            int z = 3 * zg + zi;
            size_t idx = (size_t)b * N3 + (size_t)j * N2 + (size_t)y * NN + z;
            atomicAdd(&out[idx], scale * qr[m][zi]);
        }
    }
}

extern "C" void kernel_launch(void* const* d_in, const int* in_sizes, int n_in,
                              void* d_out, int out_size, void* d_ws, size_t ws_size,
                              hipStream_t stream) {
    const float* f      = (const float*)d_in[0];
    const float* kn     = (const float*)d_in[1];
    const float* phi    = (const float*)d_in[2];
    const float* psi    = (const float*)d_in[3];
    const float* phipsi = (const float*)d_in[4];
    const int*   Mv     = (const int*)d_in[5];
    float* out = (float*)d_out;

    char* w = (char*)d_ws;
    const size_t fspecB = (size_t)NB * N3 * sizeof(cplx);            // 7,077,888
    const size_t perTB  = (size_t)NB * NH * N2 * sizeof(float4);     // 7,372,800 per t
    cplx* fspec = (cplx*)w;
    char* pool  = w + fspecB;

    const int NTOT = NT + 1;   // 20 fg terms + 1 fl term
    size_t avail = (ws_size > fspecB) ? (ws_size - fspecB) : 0;
    int chunk = (int)(avail / perTB);
    if (chunk < 1)    chunk = 1;
    if (chunk > NTOT) chunk = NTOT;
    float4* vab = (float4*)pool;

    hipMemsetAsync(out, 0, (size_t)NB * N3 * sizeof(float), stream);

    kA_f<<<dim3(NN, NB), 256, 0, stream>>>(f, fspec);
    kB_f<<<dim3(NN, NB), 256, 0, stream>>>(fspec);

    for (int t0 = 0; t0 < NTOT; t0 += chunk) {
        int cn = (t0 + chunk <= NTOT) ? chunk : (NTOT - t0);
        kAB<<<dim3(NH, NB, cn), 256, 0, stream>>>(fspec, phi, psi, phipsi, vab, t0);
        kB_all<<<dim3(NN, NB, NSL), 256, 0, stream>>>(vab, out, kn, Mv, t0, cn);
    }
}